// Round 11
// baseline (1203.024 us; speedup 1.0000x reference)
//
#include <hip/hip_runtime.h>
#include <hip/hip_bf16.h>

// ============================================================================
// R11 = METERING ROUND. Identical to R8 (best: 105 us) except the fused kernel
// body executes TWICE per dispatch, pushing its duration (~196 us) above the
// harness poison fills (~152 us) so it surfaces in the top-5 rocprof rows with
// FETCH_SIZE / WRITE_SIZE / MfmaUtil / VALUBusy / Occupancy / LDS conflicts.
// Second pass rewrites identical values -> deterministic, passes validation.
// Divide the fused kernel's FETCH/WRITE by 2 to get the real per-pass traffic.
// ============================================================================

typedef __attribute__((ext_vector_type(8))) short bf16x8;
typedef __attribute__((ext_vector_type(4))) float f32x4;

#define B    4
#define CIN  128
#define COUT 256
#define H    256
#define W    256
#define HW   (H * W)
#define ROWS 8           // output rows per block (R8 config)
#define PXW  64          // px strip per block (R8 config)

__device__ __forceinline__ unsigned short f2bf(float f) {
  unsigned int u = __builtin_bit_cast(unsigned int, f);
  u += 0x7fff + ((u >> 16) & 1);
  return (unsigned short)(u >> 16);
}

__global__ void cvt_wpw(const float* __restrict__ w, unsigned short* __restrict__ o) {
  int i = blockIdx.x * 256 + threadIdx.x;
  if (i < COUT * CIN) o[i] = f2bf(w[i]);
}

struct Row { float L; f32x4 a; f32x4 b; float R; };

__device__ __forceinline__ float rget(const Row& r, int j) {
  return (j < 0) ? r.L : (j < 4) ? r.a[j & 3] : (j < 8) ? r.b[j & 3] : r.R;
}

__device__ __forceinline__ Row load_row(const float* xr, int px0, bool pL, bool pR) {
  Row r;
  r.a = *(const f32x4*)(xr + px0);
  r.b = *(const f32x4*)(xr + px0 + 4);
  r.L = pL ? xr[px0 - 1] : 0.f;
  r.R = pR ? xr[px0 + 8] : 0.f;
  return r;
}

__device__ __forceinline__ Row zero_row() {
  Row r; r.L = r.R = 0.f;
  r.a = (f32x4){0.f,0.f,0.f,0.f};
  r.b = (f32x4){0.f,0.f,0.f,0.f};
  return r;
}

// LDS y layout: La = r*16384 + pxl*256 + ci*2 (bytes); 8x64x128 bf16 = 128 KB.
__device__ __forceinline__ unsigned swz(unsigned La) {
  unsigned g = ((La >> 8) & 7) ^ ((La >> 11) & 7);
  return La ^ (g << 4);
}

__global__ __launch_bounds__(1024, 4) void fused_kernel(
    const float* __restrict__ x, const float* __restrict__ wdw,
    const unsigned short* __restrict__ wb, float* __restrict__ out)
{
  int bid = blockIdx.x;
  int xcd = bid & 7;
  int k   = bid >> 3;          // 0..63
  int hcl = k & 3;
  int s   = (k >> 2) & 3;      // 4 strips of 64 px
  int b   = k >> 4;            // 0..3
  int hc  = xcd * 4 + hcl;     // 0..31
  int hBase = hc * ROWS;

  int t = threadIdx.x;
  int ci  = t >> 3;            // 0..127
  int pxg = t & 7;             // 0..7, 8 px each
  int px0 = s * PXW + pxg * 8; // global px
  bool pL = px0 > 0, pR = px0 + 8 < W;

  __shared__ __align__(16) char yb[ROWS * PXW * CIN * 2];   // 128 KB

  float wr[9];
#pragma unroll
  for (int q = 0; q < 9; ++q) wr[q] = wdw[ci * 9 + q];

  const float* xc = x + ((size_t)b * CIN + ci) * HW;

  // GEMM thread ids
  int wave = t >> 6, l = t & 63;
  int l15 = l & 15, lg = l >> 4;
  int coBase = wave * 16;      // 16 waves x 16 co = 256

  bf16x8 Af[4];
#pragma unroll
  for (int kk = 0; kk < 4; ++kk)
    Af[kk] = *(const bf16x8*)(wb + (coBase + l15) * CIN + kk * 32 + lg * 8);

  for (int pass = 0; pass < 2; ++pass) {
    // ---- dw phase: rolling window over 10 rows, no internal barriers ----
    Row A  = (hBase > 0) ? load_row(xc + (size_t)(hBase - 1) * W, px0, pL, pR) : zero_row();
    Row Bv = load_row(xc + (size_t)hBase * W, px0, pL, pR);
    Row C  = load_row(xc + (size_t)(hBase + 1) * W, px0, pL, pR);

#pragma unroll
    for (int r = 0; r < ROWS; ++r) {
      Row D;
      if (r < ROWS - 1) {
        int hh = hBase + r + 2;
        bool ok = hh < H;
        D = ok ? load_row(xc + (size_t)hh * W, px0, pL, pR) : zero_row();
      }

#pragma unroll
      for (int j = 0; j < 8; ++j) {
        float a =
          rget(A, j-1)*wr[0] + rget(A, j)*wr[1] + rget(A, j+1)*wr[2] +
          rget(Bv,j-1)*wr[3] + rget(Bv,j)*wr[4] + rget(Bv,j+1)*wr[5] +
          rget(C, j-1)*wr[6] + rget(C, j)*wr[7] + rget(C, j+1)*wr[8];
        unsigned La = (unsigned)r * 16384u + (unsigned)(pxg * 8 + j) * 256u + (unsigned)ci * 2u;
        *(unsigned short*)(yb + swz(La)) = f2bf(a);
      }

      if (r < ROWS - 1) { A = Bv; Bv = C; C = D; }
    }

    __syncthreads();

    // ---- GEMM phase ----
    float* ob = out + (size_t)b * COUT * HW + s * PXW;

#pragma unroll
    for (int r = 0; r < ROWS; ++r) {
      f32x4 acc[4];
#pragma unroll
      for (int n = 0; n < 4; ++n) acc[n] = (f32x4){0.f,0.f,0.f,0.f};

#pragma unroll
      for (int n = 0; n < 4; ++n) {
        bf16x8 Bf[4];
#pragma unroll
        for (int kk = 0; kk < 4; ++kk) {
          unsigned La = (unsigned)r * 16384u + (unsigned)(n * 16 + l15) * 256u
                      + (unsigned)(kk * 32 + lg * 8) * 2u;
          Bf[kk] = *(const bf16x8*)(yb + swz(La));
        }
#pragma unroll
        for (int kk = 0; kk < 4; ++kk)
          acc[n] = __builtin_amdgcn_mfma_f32_16x16x32_bf16(Af[kk], Bf[kk], acc[n], 0, 0, 0);
      }

      float* orow = ob + (size_t)(hBase + r) * W;
#pragma unroll
      for (int n = 0; n < 4; ++n)
#pragma unroll
        for (int rr = 0; rr < 4; ++rr)
          orow[(size_t)(coBase + lg * 4 + rr) * HW + n * 16 + l15] = acc[n][rr];
    }

    __syncthreads();   // protect yb against next pass's dw writes (WAR)
  }
}

extern "C" void kernel_launch(void* const* d_in, const int* in_sizes, int n_in,
                              void* d_out, int out_size, void* d_ws, size_t ws_size,
                              hipStream_t stream) {
  const float* x   = (const float*)d_in[0];
  const float* wdw = (const float*)d_in[1];
  const float* wpw = (const float*)d_in[2];
  float* out = (float*)d_out;

  unsigned short* wbb = (unsigned short*)d_ws;   // 64 KB bf16 pw weights

  cvt_wpw<<<(COUT * CIN + 255) / 256, 256, 0, stream>>>(wpw, wbb);
  fused_kernel<<<B * (H / ROWS) * (W / PXW), 1024, 0, stream>>>(x, wdw, wbb, out);
}

// Round 12
// 207.803 us; speedup vs baseline: 5.7892x; 5.7892x over previous
//
#include <hip/hip_runtime.h>
#include <hip/hip_bf16.h>

// ============================================================================
// R12 = METERING ROUND v2. Kernel body is BYTE-IDENTICAL to R8 (best: 105 us).
// The only change: 16x s_sleep(127) (~54 us) appended AFTER all real work, so
// the dispatch (~206 us) rises above the harness poison fills (~152 us) and
// surfaces in the top-5 rocprof rows. Sleeps are SALU no-def instructions at
// the kernel tail -> zero impact on hot-loop codegen, registers, or traffic.
// Counters read directly (NO division): FETCH_SIZE, WRITE_SIZE, VGPR_Count,
// SQ_LDS_BANK_CONFLICT, OccupancyPercent.
// ============================================================================

typedef __attribute__((ext_vector_type(8))) short bf16x8;
typedef __attribute__((ext_vector_type(4))) float f32x4;

#define B    4
#define CIN  128
#define COUT 256
#define H    256
#define W    256
#define HW   (H * W)
#define ROWS 8           // output rows per block (R8 config)
#define PXW  64          // px strip per block (R8 config)

__device__ __forceinline__ unsigned short f2bf(float f) {
  unsigned int u = __builtin_bit_cast(unsigned int, f);
  u += 0x7fff + ((u >> 16) & 1);
  return (unsigned short)(u >> 16);
}

__global__ void cvt_wpw(const float* __restrict__ w, unsigned short* __restrict__ o) {
  int i = blockIdx.x * 256 + threadIdx.x;
  if (i < COUT * CIN) o[i] = f2bf(w[i]);
}

struct Row { float L; f32x4 a; f32x4 b; float R; };

__device__ __forceinline__ float rget(const Row& r, int j) {
  return (j < 0) ? r.L : (j < 4) ? r.a[j & 3] : (j < 8) ? r.b[j & 3] : r.R;
}

__device__ __forceinline__ Row load_row(const float* xr, int px0, bool pL, bool pR) {
  Row r;
  r.a = *(const f32x4*)(xr + px0);
  r.b = *(const f32x4*)(xr + px0 + 4);
  r.L = pL ? xr[px0 - 1] : 0.f;
  r.R = pR ? xr[px0 + 8] : 0.f;
  return r;
}

__device__ __forceinline__ Row zero_row() {
  Row r; r.L = r.R = 0.f;
  r.a = (f32x4){0.f,0.f,0.f,0.f};
  r.b = (f32x4){0.f,0.f,0.f,0.f};
  return r;
}

// LDS y layout: La = r*16384 + pxl*256 + ci*2 (bytes); 8x64x128 bf16 = 128 KB.
__device__ __forceinline__ unsigned swz(unsigned La) {
  unsigned g = ((La >> 8) & 7) ^ ((La >> 11) & 7);
  return La ^ (g << 4);
}

__global__ __launch_bounds__(1024, 4) void fused_kernel(
    const float* __restrict__ x, const float* __restrict__ wdw,
    const unsigned short* __restrict__ wb, float* __restrict__ out)
{
  int bid = blockIdx.x;
  int xcd = bid & 7;
  int k   = bid >> 3;          // 0..63
  int hcl = k & 3;
  int s   = (k >> 2) & 3;      // 4 strips of 64 px
  int b   = k >> 4;            // 0..3
  int hc  = xcd * 4 + hcl;     // 0..31
  int hBase = hc * ROWS;

  int t = threadIdx.x;
  int ci  = t >> 3;            // 0..127
  int pxg = t & 7;             // 0..7, 8 px each
  int px0 = s * PXW + pxg * 8; // global px
  bool pL = px0 > 0, pR = px0 + 8 < W;

  __shared__ __align__(16) char yb[ROWS * PXW * CIN * 2];   // 128 KB

  float wr[9];
#pragma unroll
  for (int q = 0; q < 9; ++q) wr[q] = wdw[ci * 9 + q];

  const float* xc = x + ((size_t)b * CIN + ci) * HW;

  // ---- dw phase: rolling window over 10 rows, no internal barriers ----
  Row A  = (hBase > 0) ? load_row(xc + (size_t)(hBase - 1) * W, px0, pL, pR) : zero_row();
  Row Bv = load_row(xc + (size_t)hBase * W, px0, pL, pR);
  Row C  = load_row(xc + (size_t)(hBase + 1) * W, px0, pL, pR);

#pragma unroll
  for (int r = 0; r < ROWS; ++r) {
    Row D;
    if (r < ROWS - 1) {
      int hh = hBase + r + 2;
      bool ok = hh < H;
      D = ok ? load_row(xc + (size_t)hh * W, px0, pL, pR) : zero_row();
    }

#pragma unroll
    for (int j = 0; j < 8; ++j) {
      float a =
        rget(A, j-1)*wr[0] + rget(A, j)*wr[1] + rget(A, j+1)*wr[2] +
        rget(Bv,j-1)*wr[3] + rget(Bv,j)*wr[4] + rget(Bv,j+1)*wr[5] +
        rget(C, j-1)*wr[6] + rget(C, j)*wr[7] + rget(C, j+1)*wr[8];
      unsigned La = (unsigned)r * 16384u + (unsigned)(pxg * 8 + j) * 256u + (unsigned)ci * 2u;
      *(unsigned short*)(yb + swz(La)) = f2bf(a);
    }

    if (r < ROWS - 1) { A = Bv; Bv = C; C = D; }
  }

  // ---- GEMM phase ----
  int wave = t >> 6, l = t & 63;
  int l15 = l & 15, lg = l >> 4;
  int coBase = wave * 16;      // 16 waves x 16 co = 256

  bf16x8 Af[4];
#pragma unroll
  for (int kk = 0; kk < 4; ++kk)
    Af[kk] = *(const bf16x8*)(wb + (coBase + l15) * CIN + kk * 32 + lg * 8);

  __syncthreads();

  float* ob = out + (size_t)b * COUT * HW + s * PXW;

#pragma unroll
  for (int r = 0; r < ROWS; ++r) {
    f32x4 acc[4];
#pragma unroll
    for (int n = 0; n < 4; ++n) acc[n] = (f32x4){0.f,0.f,0.f,0.f};

#pragma unroll
    for (int n = 0; n < 4; ++n) {
      bf16x8 Bf[4];
#pragma unroll
      for (int kk = 0; kk < 4; ++kk) {
        unsigned La = (unsigned)r * 16384u + (unsigned)(n * 16 + l15) * 256u
                    + (unsigned)(kk * 32 + lg * 8) * 2u;
        Bf[kk] = *(const bf16x8*)(yb + swz(La));
      }
#pragma unroll
      for (int kk = 0; kk < 4; ++kk)
        acc[n] = __builtin_amdgcn_mfma_f32_16x16x32_bf16(Af[kk], Bf[kk], acc[n], 0, 0, 0);
    }

    float* orow = ob + (size_t)(hBase + r) * W;
#pragma unroll
    for (int n = 0; n < 4; ++n)
#pragma unroll
      for (int rr = 0; rr < 4; ++rr)
        orow[(size_t)(coBase + lg * 4 + rr) * HW + n * 16 + l15] = acc[n][rr];
  }

  // ---- time dilation (metering only): ~54 us of SALU sleep, after all work
#pragma unroll
  for (int z = 0; z < 16; ++z)
    asm volatile("s_sleep 127");
}

extern "C" void kernel_launch(void* const* d_in, const int* in_sizes, int n_in,
                              void* d_out, int out_size, void* d_ws, size_t ws_size,
                              hipStream_t stream) {
  const float* x   = (const float*)d_in[0];
  const float* wdw = (const float*)d_in[1];
  const float* wpw = (const float*)d_in[2];
  float* out = (float*)d_out;

  unsigned short* wbb = (unsigned short*)d_ws;   // 64 KB bf16 pw weights

  cvt_wpw<<<(COUT * CIN + 255) / 256, 256, 0, stream>>>(wpw, wbb);
  fused_kernel<<<B * (H / ROWS) * (W / PXW), 1024, 0, stream>>>(x, wdw, wbb, out);
}

// Round 13
// 119.803 us; speedup vs baseline: 10.0417x; 1.7345x over previous
//
#include <hip/hip_runtime.h>
#include <hip/hip_bf16.h>

typedef __attribute__((ext_vector_type(8))) short bf16x8;
typedef __attribute__((ext_vector_type(4))) float f32x4;

#define B    4
#define CIN  128
#define COUT 256
#define H    256
#define W    256
#define HW   (H * W)
#define ROWS 4           // output rows per block
#define PXW  64          // px strip per block

__device__ __forceinline__ unsigned short f2bf(float f) {
  unsigned int u = __builtin_bit_cast(unsigned int, f);
  u += 0x7fff + ((u >> 16) & 1);
  return (unsigned short)(u >> 16);
}

__global__ void cvt_wpw(const float* __restrict__ w, unsigned short* __restrict__ o) {
  int i = blockIdx.x * 256 + threadIdx.x;
  if (i < COUT * CIN) o[i] = f2bf(w[i]);
}

struct Row { float L; f32x4 a; f32x4 b; float R; };

__device__ __forceinline__ float rget(const Row& r, int j) {
  return (j < 0) ? r.L : (j < 4) ? r.a[j & 3] : (j < 8) ? r.b[j & 3] : r.R;
}

__device__ __forceinline__ Row load_row(const float* xr, int px0, bool pL, bool pR) {
  Row r;
  r.a = *(const f32x4*)(xr + px0);
  r.b = *(const f32x4*)(xr + px0 + 4);
  r.L = pL ? xr[px0 - 1] : 0.f;
  r.R = pR ? xr[px0 + 8] : 0.f;
  return r;
}

__device__ __forceinline__ Row zero_row() {
  Row r; r.L = r.R = 0.f;
  r.a = (f32x4){0.f,0.f,0.f,0.f};
  r.b = (f32x4){0.f,0.f,0.f,0.f};
  return r;
}

// LDS y layout: La = r*16384 + pxl*256 + ci*2 (bytes); 4 x 64 x 128 bf16 = 64 KB.
// swz XORs granule bits 4-6 with (pxl&7)^((pxl>>3)&7):
//   dw u16 writes -> exactly 2 lanes/bank (free; confirmed R12: conflicts ~3%)
//   GEMM b128 reads -> 64 distinct 16B granules per instr (conflict-floor)
__device__ __forceinline__ unsigned swz(unsigned La) {
  unsigned g = ((La >> 8) & 7) ^ ((La >> 11) & 7);
  return La ^ (g << 4);
}

// ---------------------------------------------------------------------------
// Fused dw3x3 + pw GEMM. R13: PHASE-OVERLAP round (R12 counters: FETCH 80MB,
// WRITE 265MB, effective BW 3.6 TB/s -> latency/phase-bound, not traffic).
// Block = 4 rows x 64 px x 128 ci; 512 thr (8 waves), 64 KB LDS,
// __launch_bounds__(512,4) -> 2 INDEPENDENT blocks/CU: dw (fetch-only) of one
// overlaps GEMM (store-only) of the other. Grid 1024 = 2 generations.
// GEMM uses SWAPPED operands: D = Y*W -> D[px][co], 4 consecutive px per
// lane -> f32x4 epilogue stores (4x fewer store issues than scalar).
// ---------------------------------------------------------------------------
__global__ __launch_bounds__(512, 4) void fused_kernel(
    const float* __restrict__ x, const float* __restrict__ wdw,
    const unsigned short* __restrict__ wb, float* __restrict__ out)
{
  int bid = blockIdx.x;
  int xcd = bid & 7;
  int k   = bid >> 3;          // 0..127
  int hcl = k & 7;
  int s   = (k >> 3) & 3;      // 4 strips of 64 px
  int b   = k >> 5;            // 0..3
  int hc  = xcd * 8 + hcl;     // 0..63
  int hBase = hc * ROWS;       // 0..252

  int t = threadIdx.x;
  int c   = t >> 3;            // 0..63 : ci-pair
  int pxg = t & 7;             // 0..7, 8 px each
  int ci0 = c * 2;
  int px0 = s * PXW + pxg * 8; // global px
  bool pL = px0 > 0, pR = px0 + 8 < W;

  __shared__ __align__(16) char yb[ROWS * PXW * CIN * 2];   // 64 KB

  // ---- dw phase: 2 ci sequentially, rolling 3-row window over 6 rows ----
#pragma unroll
  for (int cc = 0; cc < 2; ++cc) {
    int ci = ci0 + cc;
    const float* xc = x + ((size_t)b * CIN + ci) * HW;

    float wr[9];
#pragma unroll
    for (int q = 0; q < 9; ++q) wr[q] = wdw[ci * 9 + q];

    Row A  = (hBase > 0) ? load_row(xc + (size_t)(hBase - 1) * W, px0, pL, pR) : zero_row();
    Row Bv = load_row(xc + (size_t)hBase * W, px0, pL, pR);
    Row C  = load_row(xc + (size_t)(hBase + 1) * W, px0, pL, pR);   // hBase+1 <= 253

#pragma unroll
    for (int r = 0; r < ROWS; ++r) {
      Row D;
      if (r < ROWS - 1) {
        int hh = hBase + r + 2;
        bool ok = hh < H;                   // wave-uniform (last chunk only)
        D = ok ? load_row(xc + (size_t)hh * W, px0, pL, pR) : zero_row();
      }

#pragma unroll
      for (int j = 0; j < 8; ++j) {
        float a =
          rget(A, j-1)*wr[0] + rget(A, j)*wr[1] + rget(A, j+1)*wr[2] +
          rget(Bv,j-1)*wr[3] + rget(Bv,j)*wr[4] + rget(Bv,j+1)*wr[5] +
          rget(C, j-1)*wr[6] + rget(C, j)*wr[7] + rget(C, j+1)*wr[8];
        unsigned La = (unsigned)r * 16384u + (unsigned)(pxg * 8 + j) * 256u + (unsigned)ci * 2u;
        *(unsigned short*)(yb + swz(La)) = f2bf(a);
      }

      if (r < ROWS - 1) { A = Bv; Bv = C; C = D; }
    }
  }

  // ---- GEMM phase (swapped operands: D[px][co] = Y[px][ci] * W[ci][co]) ----
  int wave = t >> 6, l = t & 63;
  int l15 = l & 15, lg = l >> 4;
  int coBase = wave * 32;            // 8 waves x 32 co

  // W-operand frags: lane holds w[co = coBase+n*16+l15][ci = kk*32+lg*8+e]
  bf16x8 Wf[2][4];
#pragma unroll
  for (int n = 0; n < 2; ++n)
#pragma unroll
    for (int kk = 0; kk < 4; ++kk)
      Wf[n][kk] = *(const bf16x8*)(wb + (coBase + n * 16 + l15) * CIN + kk * 32 + lg * 8);

  __syncthreads();

  float* ob = out + (size_t)b * COUT * HW + s * PXW;

#pragma unroll
  for (int r = 0; r < ROWS; ++r) {
    f32x4 acc[4][2];
#pragma unroll
    for (int m = 0; m < 4; ++m)
#pragma unroll
      for (int n = 0; n < 2; ++n) acc[m][n] = (f32x4){0.f,0.f,0.f,0.f};

#pragma unroll
    for (int m = 0; m < 4; ++m) {
      // Y-operand frag: lane holds y[px = m*16+l15][ci = kk*32+lg*8+e]
      bf16x8 Yf[4];
#pragma unroll
      for (int kk = 0; kk < 4; ++kk) {
        unsigned La = (unsigned)r * 16384u + (unsigned)(m * 16 + l15) * 256u
                    + (unsigned)(kk * 32 + lg * 8) * 2u;
        Yf[kk] = *(const bf16x8*)(yb + swz(La));
      }
#pragma unroll
      for (int n = 0; n < 2; ++n)
#pragma unroll
        for (int kk = 0; kk < 4; ++kk)
          acc[m][n] = __builtin_amdgcn_mfma_f32_16x16x32_bf16(Yf[kk], Wf[n][kk], acc[m][n], 0, 0, 0);
    }

    // D layout: px = m*16 + lg*4 + q (q=reg), co = coBase + n*16 + l15
    float* orow = ob + (size_t)(hBase + r) * W;
#pragma unroll
    for (int m = 0; m < 4; ++m)
#pragma unroll
      for (int n = 0; n < 2; ++n)
        *(f32x4*)(orow + (size_t)(coBase + n * 16 + l15) * HW + m * 16 + lg * 4) = acc[m][n];
  }
}

extern "C" void kernel_launch(void* const* d_in, const int* in_sizes, int n_in,
                              void* d_out, int out_size, void* d_ws, size_t ws_size,
                              hipStream_t stream) {
  const float* x   = (const float*)d_in[0];
  const float* wdw = (const float*)d_in[1];
  const float* wpw = (const float*)d_in[2];
  float* out = (float*)d_out;

  unsigned short* wbb = (unsigned short*)d_ws;   // 64 KB bf16 pw weights

  cvt_wpw<<<(COUT * CIN + 255) / 256, 256, 0, stream>>>(wpw, wbb);
  fused_kernel<<<B * (H / ROWS) * (W / PXW), 512, 0, stream>>>(x, wdw, wbb, out);
}